// Round 3
// baseline (26330.923 us; speedup 1.0000x reference)
//
#include <hip/hip_runtime.h>
#include <hip/hip_cooperative_groups.h>
#include <hip/hip_bf16.h>
#include <math.h>

namespace cg = cooperative_groups;

// Problem dims (fixed by reference)
#define B 128
#define T 64
#define H 512
#define O 47
#define PP 4
#define G 2048   // 4*H
#define HB (H*B) // 65536

// ===========================================================================
// PERSISTENT PATH
// ---------------------------------------------------------------------------
// Folding: nxt(t) = enc(dec(h2(t))) = h2(t) @ M^T + d,
//   M[h,k] = sum_o enc_w[h,o] dec_w[o,k],  d[h] = enc_b[h] + sum_o enc_w[h,o] dec_b[o]
// Layer-0 x-part for t>=1:  W0eff = w_ih0[:, :H] @ M   (2048x512),
//   constant part cd[j] = w_ih0[:, :H] @ d folded into biasB.
// t=0 x-part: x0c[j] = w_ih0[:, :H] @ nxt0 (batch-independent), folded into biasA.
// Props part (time-constant): propc[j,b] folded into both bias planes.
// => every step is exactly 3 GEMM phases; logits ride phase L0 as 47 extra
//    rows reusing the same x (=h2prev) loads.
// ROUND-2 FIX: logits write (dout) must be gated on rg < O — previously WGs
// rg in [47,128) stored uninitialized LDS sums into d_out (absmax 9.4e4).
// ===========================================================================

struct RnnParams {
  const float* w_hh0;   // [G][H]
  const float* w_ihr;   // [2][G][H]
  const float* w_hhr;   // [2][G][H]
  const float* b_ihr;   // [2][G]
  const float* b_hhr;   // [2][G]
  const float* dec_w;   // [O][H]
  const float* dec_b;   // [O]
  const float* W0eff;   // [G][H]
  const float* biasA;   // [G][B]  (t==0 plane)
  const float* biasB;   // [G][B]  (t>=1 plane)
  float* h;             // 6*HB  (h0p,h0c,h1p,h1c,h2p,h2c)
  float* c;             // 3*HB
  float* out;           // [B][T][O]
};

// ---- precompute kernels ----------------------------------------------------

__global__ __launch_bounds__(256) void k_init(
    const float* __restrict__ enc_w, const float* __restrict__ enc_b,
    const float* __restrict__ dec_b,
    float* __restrict__ h, float* __restrict__ c,
    float* __restrict__ d, float* __restrict__ nxt0)
{
    int idx = blockIdx.x * 256 + threadIdx.x;   // grid 256 -> HB threads
    #pragma unroll
    for (int i = 0; i < 6; ++i) h[i*HB + idx] = 0.f;
    #pragma unroll
    for (int i = 0; i < 3; ++i) c[i*HB + idx] = 0.f;
    if (idx < H) {
        float s = 0.f;
        for (int o = 0; o < O; ++o) s += enc_w[idx*O + o] * dec_b[o];
        d[idx] = enc_b[idx] + s;
        nxt0[idx] = enc_w[idx*O + 1] + enc_b[idx];   // enc(one-hot(1))
    }
}

__global__ __launch_bounds__(256) void k_M(
    const float* __restrict__ enc_w, const float* __restrict__ dec_w,
    float* __restrict__ M)
{
    int idx = blockIdx.x * 256 + threadIdx.x;   // grid 1024 -> 512*512
    int hh = idx >> 9, k = idx & 511;
    float s = 0.f;
    for (int o = 0; o < O; ++o) s += enc_w[hh*O + o] * dec_w[o*H + k];
    M[hh*H + k] = s;
}

__global__ __launch_bounds__(256) void k_cd(
    const float* __restrict__ w_ih0,   // [G][H+PP]
    const float* __restrict__ nxt0, const float* __restrict__ d,
    float* __restrict__ x0c, float* __restrict__ cd)
{
    int j = blockIdx.x * 256 + threadIdx.x;   // grid 8 -> 2048
    const float* row = w_ih0 + (size_t)j * (H + PP);
    float sA = 0.f, sB = 0.f;
    for (int k = 0; k < H; ++k) { float w = row[k]; sA += w * nxt0[k]; sB += w * d[k]; }
    x0c[j] = sA; cd[j] = sB;
}

__global__ __launch_bounds__(256) void k_W0eff(
    const float* __restrict__ w_ih0,   // [G][H+PP]
    const float* __restrict__ M,       // [H][H]
    float* __restrict__ W0eff)         // [G][H]
{
    // block covers 16 j-rows x 512 k; thread: 8 rows x 4 k (float4)
    int k0 = (threadIdx.x & 127) * 4;
    int jsub = threadIdx.x >> 7;                 // 0/1
    int j0 = blockIdx.x * 16 + jsub * 8;         // grid 128
    float4 a[8];
    #pragma unroll
    for (int i = 0; i < 8; ++i) a[i] = make_float4(0.f, 0.f, 0.f, 0.f);
    for (int hh = 0; hh < H; ++hh) {
        float4 mv = *(const float4*)(M + (size_t)hh * H + k0);
        #pragma unroll
        for (int i = 0; i < 8; ++i) {
            float w = w_ih0[(size_t)(j0 + i) * (H + PP) + hh];
            a[i].x += w * mv.x; a[i].y += w * mv.y;
            a[i].z += w * mv.z; a[i].w += w * mv.w;
        }
    }
    #pragma unroll
    for (int i = 0; i < 8; ++i)
        *(float4*)(W0eff + (size_t)(j0 + i) * H + k0) = a[i];
}

__global__ __launch_bounds__(256) void k_bias(
    const float* __restrict__ w_ih0, const float* __restrict__ props,
    const float* __restrict__ b_ih0, const float* __restrict__ b_hh0,
    const float* __restrict__ x0c, const float* __restrict__ cd,
    float* __restrict__ biasA, float* __restrict__ biasB)
{
    int idx = blockIdx.x * 256 + threadIdx.x;   // grid 1024 -> G*B
    int j = idx >> 7, b = idx & 127;
    const float* wp = w_ih0 + (size_t)j * (H + PP) + H;
    const float* pr = props + b * PP;
    float pc = wp[0]*pr[0] + wp[1]*pr[1] + wp[2]*pr[2] + wp[3]*pr[3];
    float base = b_ih0[j] + b_hh0[j] + pc;
    biasA[idx] = base + x0c[j];
    biasB[idx] = base + cd[j];
}

// ---- the persistent kernel -------------------------------------------------

__global__ __launch_bounds__(512) void rnn_persistent(RnnParams p)
{
    cg::grid_group grid = cg::this_grid();
    const int tid  = threadIdx.x;
    const int wg   = blockIdx.x;
    const int bh   = wg >> 7;          // batch half
    const int rg   = wg & 127;         // row group: units m0..m0+3
    const int m0   = rg * 4;
    const int lane = tid & 63;
    const int ks   = tid >> 6;         // 0..7 k-slice (wave-uniform)
    const int bb   = (bh << 6) + lane; // global batch

    __shared__ float gbuf[16][8][64];  // 32 KB
    __shared__ float decbuf[8][64];    // 2 KB

    float* h0p = p.h + 0*HB; float* h0c = p.h + 1*HB;
    float* h1p = p.h + 2*HB; float* h1c = p.h + 3*HB;
    float* h2p = p.h + 4*HB; float* h2c = p.h + 5*HB;
    float* c0 = p.c; float* c1 = p.c + HB; float* c2 = p.c + 2*HB;

    const bool   isdec    = (rg < O);
    const float* decrow_w = isdec ? (p.dec_w + (size_t)rg * H) : nullptr;
    const float  decb     = isdec ? p.dec_b[rg] : 0.f;

    auto phase = [&](const float* __restrict__ xT, const float* __restrict__ hT,
                     const float* __restrict__ wih, const float* __restrict__ whh,
                     const float* __restrict__ biasPB,
                     const float* __restrict__ bia, const float* __restrict__ bib,
                     float* __restrict__ cc, float* __restrict__ hh,
                     const float* __restrict__ decrow, float* __restrict__ dout) {
        float acc[16];
        #pragma unroll
        for (int r = 0; r < 16; ++r) acc[r] = 0.f;
        float accd = 0.f;

        const float* wr[16]; const float* hr[16];
        #pragma unroll
        for (int q = 0; q < 4; ++q)
            #pragma unroll
            for (int mi = 0; mi < 4; ++mi) {
                int j = q*H + m0 + mi;
                wr[q*4+mi] = wih + (size_t)j * H;
                hr[q*4+mi] = whh + (size_t)j * H;
            }
        const int kbeg = ks * 64, kend = ks * 64 + 64;

        // pass A: x-part (K=512) (+ dec row piggyback on the same x loads)
        if (decrow) {
            for (int k0 = kbeg; k0 < kend; k0 += 4) {
                float x0 = xT[(k0+0)*B + bb], x1 = xT[(k0+1)*B + bb];
                float x2 = xT[(k0+2)*B + bb], x3 = xT[(k0+3)*B + bb];
                float4 dv = *(const float4*)(decrow + k0);
                accd += dv.x*x0 + dv.y*x1 + dv.z*x2 + dv.w*x3;
                #pragma unroll
                for (int r = 0; r < 16; ++r) {
                    float4 wv = *(const float4*)(wr[r] + k0);
                    acc[r] += wv.x*x0 + wv.y*x1 + wv.z*x2 + wv.w*x3;
                }
            }
        } else {
            for (int k0 = kbeg; k0 < kend; k0 += 4) {
                float x0 = xT[(k0+0)*B + bb], x1 = xT[(k0+1)*B + bb];
                float x2 = xT[(k0+2)*B + bb], x3 = xT[(k0+3)*B + bb];
                #pragma unroll
                for (int r = 0; r < 16; ++r) {
                    float4 wv = *(const float4*)(wr[r] + k0);
                    acc[r] += wv.x*x0 + wv.y*x1 + wv.z*x2 + wv.w*x3;
                }
            }
        }
        // pass B: h-part (K=512)
        for (int k0 = kbeg; k0 < kend; k0 += 4) {
            float x0 = hT[(k0+0)*B + bb], x1 = hT[(k0+1)*B + bb];
            float x2 = hT[(k0+2)*B + bb], x3 = hT[(k0+3)*B + bb];
            #pragma unroll
            for (int r = 0; r < 16; ++r) {
                float4 wv = *(const float4*)(hr[r] + k0);
                acc[r] += wv.x*x0 + wv.y*x1 + wv.z*x2 + wv.w*x3;
            }
        }

        #pragma unroll
        for (int r = 0; r < 16; ++r) gbuf[r][ks][lane] = acc[r];
        if (decrow) decbuf[ks][lane] = accd;
        __syncthreads();

        if (tid < 256) {
            int mi = tid >> 6, b = tid & 63;
            int bbo = (bh << 6) + b;
            int m = m0 + mi;
            float g[4];
            #pragma unroll
            for (int q = 0; q < 4; ++q) {
                int j = q*H + m;
                float s = biasPB ? biasPB[(size_t)j*B + bbo] : (bia[j] + bib[j]);
                #pragma unroll
                for (int k2 = 0; k2 < 8; ++k2) s += gbuf[q*4+mi][k2][b];
                g[q] = s;
            }
            float ig = 1.f/(1.f+expf(-g[0]));
            float fg = 1.f/(1.f+expf(-g[1]));
            float gv = tanhf(g[2]);
            float og = 1.f/(1.f+expf(-g[3]));
            int idx = m*B + bbo;
            float cn = fg*cc[idx] + ig*gv;
            cc[idx] = cn;
            hh[idx] = og*tanhf(cn);
        }
        if (decrow && dout && tid < 64) {   // FIX: only dec row-groups write
            float s = decb;
            #pragma unroll
            for (int k2 = 0; k2 < 8; ++k2) s += decbuf[k2][tid];
            dout[(size_t)((bh<<6) + tid) * (T*O)] = s;
        }
    };

    for (int t = 0; t < T; ++t) {
        // L0: x = h2(t-1) via folded W0eff (zero at t=0; bias plane handles t=0)
        phase(h2p, h0p, p.W0eff, p.w_hh0,
              (t == 0) ? p.biasA : p.biasB, nullptr, nullptr,
              c0, h0c,
              (t > 0) ? decrow_w : nullptr,
              (t > 0 && isdec) ? (p.out + (size_t)(t-1)*O + rg) : nullptr);
        __threadfence(); grid.sync(); __threadfence();
        // L1
        phase(h0c, h1p, p.w_ihr, p.w_hhr, nullptr, p.b_ihr, p.b_hhr,
              c1, h1c, nullptr, nullptr);
        __threadfence(); grid.sync(); __threadfence();
        // L2
        phase(h1c, h2p, p.w_ihr + (size_t)G*H, p.w_hhr + (size_t)G*H, nullptr,
              p.b_ihr + G, p.b_hhr + G, c2, h2c, nullptr, nullptr);
        __threadfence(); grid.sync(); __threadfence();

        float* tp;
        tp = h0p; h0p = h0c; h0c = tp;
        tp = h1p; h1p = h1c; h1c = tp;
        tp = h2p; h2p = h2c; h2c = tp;
    }

    // final logits: out[:, 63, :] = dec(h2(63)) ; h2p == h2(63) after swap
    if (isdec) {
        float accd = 0.f;
        for (int k0 = ks*64; k0 < ks*64 + 64; k0 += 4) {
            float x0 = h2p[(k0+0)*B + bb], x1 = h2p[(k0+1)*B + bb];
            float x2 = h2p[(k0+2)*B + bb], x3 = h2p[(k0+3)*B + bb];
            float4 dv = *(const float4*)(decrow_w + k0);
            accd += dv.x*x0 + dv.y*x1 + dv.z*x2 + dv.w*x3;
        }
        decbuf[ks][lane] = accd;
        __syncthreads();
        if (tid < 64) {
            float s = decb;
            #pragma unroll
            for (int k2 = 0; k2 < 8; ++k2) s += decbuf[k2][tid];
            p.out[((size_t)((bh<<6) + tid) * T + 63) * O + rg] = s;
        }
    }
}

// ===========================================================================
// LEGACY FALLBACK (round-0, proven correct) — used only if ws_size too small
// ===========================================================================

__global__ __launch_bounds__(256) void init_kernel(
    const float* __restrict__ enc_w, const float* __restrict__ enc_b,
    float* __restrict__ nxtT, float* __restrict__ hbufs, float* __restrict__ cbufs)
{
    int idx = blockIdx.x * 256 + threadIdx.x;
    #pragma unroll
    for (int i = 0; i < 6; ++i) hbufs[i * HB + idx] = 0.f;
    #pragma unroll
    for (int i = 0; i < 3; ++i) cbufs[i * HB + idx] = 0.f;
    int h = idx >> 7;
    nxtT[idx] = enc_w[h * O + 1] + enc_b[h];
}

__global__ __launch_bounds__(256) void transpose_kernel(
    const float* __restrict__ dec_w, const float* __restrict__ enc_w,
    float* __restrict__ dec_wT, float* __restrict__ enc_wT)
{
    int idx = blockIdx.x * 256 + threadIdx.x;
    if (idx < O * H) {
        int o = idx / H, k = idx - o * H;
        dec_wT[k * O + o] = dec_w[o * H + k];
        enc_wT[o * H + k] = enc_w[k * O + o];
    }
}

__global__ __launch_bounds__(512) void gates_kernel(
    const float* __restrict__ xT, const float* __restrict__ hT,
    const float* __restrict__ w_ih, int ldih,
    const float* __restrict__ w_hh,
    const float* __restrict__ b_ih, const float* __restrict__ b_hh,
    const float* __restrict__ props,
    float* __restrict__ c, float* __restrict__ hout)
{
    const int wg = blockIdx.x;
    const int bg = wg >> 7, jg = wg & 127;
    const int m0 = jg * 4;
    const int lane_b = threadIdx.x & 63, ks = threadIdx.x >> 6;
    const int bb = (bg << 6) + lane_b;
    float acc[16];
    #pragma unroll
    for (int r = 0; r < 16; ++r) acc[r] = 0.f;
    const float* wih_rows[16]; const float* whh_rows[16];
    #pragma unroll
    for (int q = 0; q < 4; ++q)
        #pragma unroll
        for (int mi = 0; mi < 4; ++mi) {
            int r = q * 4 + mi, j = q * H + m0 + mi;
            wih_rows[r] = w_ih + (size_t)j * ldih;
            whh_rows[r] = w_hh + (size_t)j * H;
        }
    const int kbeg = ks * 64, kend = ks * 64 + 64;
    for (int k0 = kbeg; k0 < kend; k0 += 4) {
        float x0 = xT[(k0+0)*B+bb], x1 = xT[(k0+1)*B+bb];
        float x2 = xT[(k0+2)*B+bb], x3 = xT[(k0+3)*B+bb];
        #pragma unroll
        for (int r = 0; r < 16; ++r) {
            float4 wv = *(const float4*)(wih_rows[r] + k0);
            acc[r] += wv.x*x0 + wv.y*x1 + wv.z*x2 + wv.w*x3;
        }
    }
    for (int k0 = kbeg; k0 < kend; k0 += 4) {
        float x0 = hT[(k0+0)*B+bb], x1 = hT[(k0+1)*B+bb];
        float x2 = hT[(k0+2)*B+bb], x3 = hT[(k0+3)*B+bb];
        #pragma unroll
        for (int r = 0; r < 16; ++r) {
            float4 wv = *(const float4*)(whh_rows[r] + k0);
            acc[r] += wv.x*x0 + wv.y*x1 + wv.z*x2 + wv.w*x3;
        }
    }
    __shared__ float gbuf[16][8][64];
    #pragma unroll
    for (int r = 0; r < 16; ++r) gbuf[r][ks][lane_b] = acc[r];
    __syncthreads();
    if (threadIdx.x < 256) {
        int mi = threadIdx.x >> 6, b = threadIdx.x & 63;
        int bbo = (bg << 6) + b, m = m0 + mi;
        float g[4];
        #pragma unroll
        for (int q = 0; q < 4; ++q) {
            int j = q * H + m;
            float s = b_ih[j] + b_hh[j];
            #pragma unroll
            for (int k2 = 0; k2 < 8; ++k2) s += gbuf[q*4+mi][k2][b];
            if (props) {
                const float* wp = w_ih + (size_t)j * ldih + H;
                const float* pp = props + bbo * PP;
                s += wp[0]*pp[0] + wp[1]*pp[1] + wp[2]*pp[2] + wp[3]*pp[3];
            }
            g[q] = s;
        }
        float ig = 1.f/(1.f+expf(-g[0]));
        float fg = 1.f/(1.f+expf(-g[1]));
        float gv = tanhf(g[2]);
        float og = 1.f/(1.f+expf(-g[3]));
        int idx = m * B + bbo;
        float cn = fg * c[idx] + ig * gv;
        c[idx] = cn;
        hout[idx] = og * tanhf(cn);
    }
}

__global__ __launch_bounds__(256) void decenc_kernel(
    const float* __restrict__ h2T, const float* __restrict__ dec_wT,
    const float* __restrict__ dec_b, const float* __restrict__ enc_wT,
    const float* __restrict__ enc_b, float* __restrict__ nxtT,
    float* __restrict__ out, int t)
{
    const int b = blockIdx.x;
    const int w = threadIdx.x >> 6, o = threadIdx.x & 63;
    __shared__ float red[4][64];
    __shared__ float lg[64];
    float p = 0.f;
    if (o < O)
        for (int k = w * 128; k < w * 128 + 128; ++k)
            p += h2T[k * B + b] * dec_wT[k * O + o];
    red[w][o] = p;
    __syncthreads();
    if (threadIdx.x < 64) {
        int oo = threadIdx.x;
        float s = 0.f;
        if (oo < O) {
            s = dec_b[oo] + red[0][oo] + red[1][oo] + red[2][oo] + red[3][oo];
            out[((size_t)b * T + t) * O + oo] = s;
        }
        lg[oo] = s;
    }
    __syncthreads();
    for (int h = threadIdx.x; h < H; h += 256) {
        float s = enc_b[h];
        #pragma unroll 1
        for (int oo = 0; oo < O; ++oo) s += lg[oo] * enc_wT[oo * H + h];
        nxtT[h * B + b] = s;
    }
}

// ===========================================================================
extern "C" void kernel_launch(void* const* d_in, const int* in_sizes, int n_in,
                              void* d_out, int out_size, void* d_ws, size_t ws_size,
                              hipStream_t stream) {
    const float* props = (const float*)d_in[1];
    const float* enc_w = (const float*)d_in[2];
    const float* enc_b = (const float*)d_in[3];
    const float* dec_w = (const float*)d_in[4];
    const float* dec_b = (const float*)d_in[5];
    const float* w_ih0 = (const float*)d_in[6];
    const float* w_hh0 = (const float*)d_in[7];
    const float* b_ih0 = (const float*)d_in[8];
    const float* b_hh0 = (const float*)d_in[9];
    const float* w_ihr = (const float*)d_in[10];
    const float* w_hhr = (const float*)d_in[11];
    const float* b_ihr = (const float*)d_in[12];
    const float* b_hhr = (const float*)d_in[13];

    float* ws = (float*)d_ws;

    // persistent-path workspace layout (floats)
    //  [0,6HB)      h ping-pong          [6HB,9HB)   c
    //  [9HB,13HB)   M (512x512)          [13HB,29HB) W0eff (2048x512)
    //  [29HB,33HB)  biasA                [33HB,37HB) biasB
    //  [37HB, +5120) d, nxt0, x0c, cd
    const size_t NEED = ((size_t)37 * HB + 5120) * sizeof(float);

    if (ws_size >= NEED) {
        float* hbuf  = ws;
        float* cbuf  = ws + 6*HB;
        float* M     = ws + 9*HB;
        float* W0eff = ws + 13*HB;
        float* biasA = ws + 29*HB;
        float* biasB = ws + 33*HB;
        float* dvec  = ws + 37*HB;
        float* nxt0  = dvec + 512;
        float* x0c   = nxt0 + 512;
        float* cd    = x0c + 2048;

        k_init<<<256, 256, 0, stream>>>(enc_w, enc_b, dec_b, hbuf, cbuf, dvec, nxt0);
        k_M<<<1024, 256, 0, stream>>>(enc_w, dec_w, M);
        k_cd<<<8, 256, 0, stream>>>(w_ih0, nxt0, dvec, x0c, cd);
        k_W0eff<<<128, 256, 0, stream>>>(w_ih0, M, W0eff);
        k_bias<<<1024, 256, 0, stream>>>(w_ih0, props, b_ih0, b_hh0, x0c, cd, biasA, biasB);

        RnnParams prm;
        prm.w_hh0 = w_hh0; prm.w_ihr = w_ihr; prm.w_hhr = w_hhr;
        prm.b_ihr = b_ihr; prm.b_hhr = b_hhr;
        prm.dec_w = dec_w; prm.dec_b = dec_b;
        prm.W0eff = W0eff; prm.biasA = biasA; prm.biasB = biasB;
        prm.h = hbuf; prm.c = cbuf; prm.out = (float*)d_out;

        void* args[] = { &prm };
        hipLaunchCooperativeKernel((const void*)rnn_persistent,
                                   dim3(256), dim3(512), args, 0, stream);
        return;
    }

    // ---- legacy multi-launch fallback ----
    float* nxtT   = ws;
    float* hb     = ws + HB;
    float* cb     = ws + 7*HB;
    float* dec_wT = ws + 10*HB;
    float* enc_wT = dec_wT + H*O;

    init_kernel<<<256, 256, 0, stream>>>(enc_w, enc_b, nxtT, hb, cb);
    transpose_kernel<<<(O*H + 255)/256, 256, 0, stream>>>(dec_w, enc_w, dec_wT, enc_wT);

    float* hprev[3]; float* hcur[3];
    for (int l = 0; l < 3; ++l) { hprev[l] = hb + (2*l)*HB; hcur[l] = hb + (2*l+1)*HB; }

    for (int t = 0; t < T; ++t) {
        gates_kernel<<<256, 512, 0, stream>>>(nxtT, hprev[0], w_ih0, H+PP, w_hh0,
                                              b_ih0, b_hh0, props, cb, hcur[0]);
        gates_kernel<<<256, 512, 0, stream>>>(hcur[0], hprev[1], w_ihr, H, w_hhr,
                                              b_ihr, b_hhr, nullptr, cb + HB, hcur[1]);
        gates_kernel<<<256, 512, 0, stream>>>(hcur[1], hprev[2], w_ihr + (size_t)G*H, H,
                                              w_hhr + (size_t)G*H, b_ihr + G, b_hhr + G,
                                              nullptr, cb + 2*HB, hcur[2]);
        decenc_kernel<<<B, 256, 0, stream>>>(hcur[2], dec_wT, dec_b, enc_wT, enc_b,
                                             nxtT, (float*)d_out, t);
        for (int l = 0; l < 3; ++l) { float* tp = hprev[l]; hprev[l] = hcur[l]; hcur[l] = tp; }
    }
}

// Round 4
// 10576.667 us; speedup vs baseline: 2.4895x; 2.4895x over previous
//
#include <hip/hip_runtime.h>
#include <hip/hip_bf16.h>
#include <math.h>

// Problem dims (fixed by reference)
#define B 128
#define T 64
#define H 512
#define O 47
#define PP 4
#define G 2048   // 4*H
#define HB (H*B) // 65536

// ===========================================================================
// PERSISTENT PATH, round 3: custom lightweight grid barrier.
// ---------------------------------------------------------------------------
// Round-2 counters: grid.sync() + threadfence cost ~110us each and invalidate
// L2 every phase (FETCH_SIZE == 192 x 6MB == full weight refetch per phase).
// Fix: no cache-wide fences at all.
//  - barrier: monotonic counter, one RELEASE agent atomicAdd per WG + spin on
//    RELAXED agent atomic load (no acquire fence => no L2 invalidate).
//  - cross-WG state (h ping-pong): per-access agent-scope relaxed atomic
//    load/store (sc0 sc1 on the access) => coherent through IF, weights stay
//    cached in L2 across all 192 phases.
//  - c-state is only ever touched by its owning WG => plain cached.
// Folding (round 1, verified): nxt = enc(dec(h2)) folded into W0eff/bias
// planes; logits ride phase L0; 3 phases/step, 192 barriers total.
// ===========================================================================

__device__ __forceinline__ float cload(const float* p) {
    return __hip_atomic_load((float*)p, __ATOMIC_RELAXED, __HIP_MEMORY_SCOPE_AGENT);
}
__device__ __forceinline__ void cstore(float* p, float v) {
    __hip_atomic_store(p, v, __ATOMIC_RELAXED, __HIP_MEMORY_SCOPE_AGENT);
}

struct RnnParams {
  const float* w_hh0;   // [G][H]
  const float* w_ihr;   // [2][G][H]
  const float* w_hhr;   // [2][G][H]
  const float* b_ihr;   // [2][G]
  const float* b_hhr;   // [2][G]
  const float* dec_w;   // [O][H]
  const float* dec_b;   // [O]
  const float* W0eff;   // [G][H]
  const float* biasA;   // [G][B]  (t==0 plane)
  const float* biasB;   // [G][B]  (t>=1 plane)
  float* h;             // 6*HB  (h0p,h0c,h1p,h1c,h2p,h2c)
  float* c;             // 3*HB
  float* out;           // [B][T][O]
  unsigned int* barcnt; // grid barrier counter (zeroed by k_init)
};

// ---- precompute kernels ----------------------------------------------------

__global__ __launch_bounds__(256) void k_init(
    const float* __restrict__ enc_w, const float* __restrict__ enc_b,
    const float* __restrict__ dec_b,
    float* __restrict__ h, float* __restrict__ c,
    float* __restrict__ d, float* __restrict__ nxt0,
    unsigned int* __restrict__ barcnt)
{
    int idx = blockIdx.x * 256 + threadIdx.x;   // grid 256 -> HB threads
    if (idx == 0) *barcnt = 0u;
    #pragma unroll
    for (int i = 0; i < 6; ++i) h[i*HB + idx] = 0.f;
    #pragma unroll
    for (int i = 0; i < 3; ++i) c[i*HB + idx] = 0.f;
    if (idx < H) {
        float s = 0.f;
        for (int o = 0; o < O; ++o) s += enc_w[idx*O + o] * dec_b[o];
        d[idx] = enc_b[idx] + s;
        nxt0[idx] = enc_w[idx*O + 1] + enc_b[idx];   // enc(one-hot(1))
    }
}

__global__ __launch_bounds__(256) void k_M(
    const float* __restrict__ enc_w, const float* __restrict__ dec_w,
    float* __restrict__ M)
{
    int idx = blockIdx.x * 256 + threadIdx.x;   // grid 1024 -> 512*512
    int hh = idx >> 9, k = idx & 511;
    float s = 0.f;
    for (int o = 0; o < O; ++o) s += enc_w[hh*O + o] * dec_w[o*H + k];
    M[hh*H + k] = s;
}

__global__ __launch_bounds__(256) void k_cd(
    const float* __restrict__ w_ih0,   // [G][H+PP]
    const float* __restrict__ nxt0, const float* __restrict__ d,
    float* __restrict__ x0c, float* __restrict__ cd)
{
    int j = blockIdx.x * 256 + threadIdx.x;   // grid 8 -> 2048
    const float* row = w_ih0 + (size_t)j * (H + PP);
    float sA = 0.f, sB = 0.f;
    for (int k = 0; k < H; ++k) { float w = row[k]; sA += w * nxt0[k]; sB += w * d[k]; }
    x0c[j] = sA; cd[j] = sB;
}

__global__ __launch_bounds__(256) void k_W0eff(
    const float* __restrict__ w_ih0,   // [G][H+PP]
    const float* __restrict__ M,       // [H][H]
    float* __restrict__ W0eff)         // [G][H]
{
    int k0 = (threadIdx.x & 127) * 4;
    int jsub = threadIdx.x >> 7;                 // 0/1
    int j0 = blockIdx.x * 16 + jsub * 8;         // grid 128
    float4 a[8];
    #pragma unroll
    for (int i = 0; i < 8; ++i) a[i] = make_float4(0.f, 0.f, 0.f, 0.f);
    for (int hh = 0; hh < H; ++hh) {
        float4 mv = *(const float4*)(M + (size_t)hh * H + k0);
        #pragma unroll
        for (int i = 0; i < 8; ++i) {
            float w = w_ih0[(size_t)(j0 + i) * (H + PP) + hh];
            a[i].x += w * mv.x; a[i].y += w * mv.y;
            a[i].z += w * mv.z; a[i].w += w * mv.w;
        }
    }
    #pragma unroll
    for (int i = 0; i < 8; ++i)
        *(float4*)(W0eff + (size_t)(j0 + i) * H + k0) = a[i];
}

__global__ __launch_bounds__(256) void k_bias(
    const float* __restrict__ w_ih0, const float* __restrict__ props,
    const float* __restrict__ b_ih0, const float* __restrict__ b_hh0,
    const float* __restrict__ x0c, const float* __restrict__ cd,
    float* __restrict__ biasA, float* __restrict__ biasB)
{
    int idx = blockIdx.x * 256 + threadIdx.x;   // grid 1024 -> G*B
    int j = idx >> 7, b = idx & 127;
    const float* wp = w_ih0 + (size_t)j * (H + PP) + H;
    const float* pr = props + b * PP;
    float pc = wp[0]*pr[0] + wp[1]*pr[1] + wp[2]*pr[2] + wp[3]*pr[3];
    float base = b_ih0[j] + b_hh0[j] + pc;
    biasA[idx] = base + x0c[j];
    biasB[idx] = base + cd[j];
}

// ---- the persistent kernel -------------------------------------------------

__global__ __launch_bounds__(512) void rnn_persistent(RnnParams p)
{
    const int tid  = threadIdx.x;
    const int wg   = blockIdx.x;
    const int bh   = wg >> 7;          // batch half
    const int rg   = wg & 127;         // row group: units m0..m0+3
    const int m0   = rg * 4;
    const int lane = tid & 63;
    const int ks   = tid >> 6;         // 0..7 k-slice (wave-uniform)
    const int bb   = (bh << 6) + lane; // global batch

    __shared__ float gbuf[16][8][64];  // 32 KB
    __shared__ float decbuf[8][64];    // 2 KB

    float* h0p = p.h + 0*HB; float* h0c = p.h + 1*HB;
    float* h1p = p.h + 2*HB; float* h1c = p.h + 3*HB;
    float* h2p = p.h + 4*HB; float* h2c = p.h + 5*HB;
    float* c0 = p.c; float* c1 = p.c + HB; float* c2 = p.c + 2*HB;

    const bool   isdec    = (rg < O);
    const float* decrow_w = isdec ? (p.dec_w + (size_t)rg * H) : nullptr;
    const float  decb     = isdec ? p.dec_b[rg] : 0.f;

    unsigned int bartgt = 0;
    unsigned int* cnt = p.barcnt;

    // lightweight grid barrier: monotonic counter, no cache-wide fences.
    auto gbar = [&]() {
        bartgt += 256;                 // 256 WGs arrive per barrier
        __syncthreads();               // per-wave vmem drained before s_barrier
        if (tid == 0) {
            __hip_atomic_fetch_add(cnt, 1u, __ATOMIC_RELEASE, __HIP_MEMORY_SCOPE_AGENT);
            while (__hip_atomic_load(cnt, __ATOMIC_RELAXED, __HIP_MEMORY_SCOPE_AGENT) < bartgt)
                __builtin_amdgcn_s_sleep(1);
        }
        __syncthreads();
    };

    auto phase = [&](const float* __restrict__ xT, const float* __restrict__ hT,
                     const float* __restrict__ wih, const float* __restrict__ whh,
                     const float* __restrict__ biasPB,
                     const float* __restrict__ bia, const float* __restrict__ bib,
                     float* __restrict__ cc, float* __restrict__ hh,
                     const float* __restrict__ decrow, float* __restrict__ dout) {
        float acc[16];
        #pragma unroll
        for (int r = 0; r < 16; ++r) acc[r] = 0.f;
        float accd = 0.f;

        const float* wr[16]; const float* hr[16];
        #pragma unroll
        for (int q = 0; q < 4; ++q)
            #pragma unroll
            for (int mi = 0; mi < 4; ++mi) {
                int j = q*H + m0 + mi;
                wr[q*4+mi] = wih + (size_t)j * H;
                hr[q*4+mi] = whh + (size_t)j * H;
            }
        const int kbeg = ks * 64, kend = ks * 64 + 64;

        // pass A: x-part (state read: coherent agent loads; weights cached)
        if (decrow) {
            for (int k0 = kbeg; k0 < kend; k0 += 4) {
                float x0 = cload(&xT[(k0+0)*B + bb]), x1 = cload(&xT[(k0+1)*B + bb]);
                float x2 = cload(&xT[(k0+2)*B + bb]), x3 = cload(&xT[(k0+3)*B + bb]);
                float4 dv = *(const float4*)(decrow + k0);
                accd += dv.x*x0 + dv.y*x1 + dv.z*x2 + dv.w*x3;
                #pragma unroll
                for (int r = 0; r < 16; ++r) {
                    float4 wv = *(const float4*)(wr[r] + k0);
                    acc[r] += wv.x*x0 + wv.y*x1 + wv.z*x2 + wv.w*x3;
                }
            }
        } else {
            for (int k0 = kbeg; k0 < kend; k0 += 4) {
                float x0 = cload(&xT[(k0+0)*B + bb]), x1 = cload(&xT[(k0+1)*B + bb]);
                float x2 = cload(&xT[(k0+2)*B + bb]), x3 = cload(&xT[(k0+3)*B + bb]);
                #pragma unroll
                for (int r = 0; r < 16; ++r) {
                    float4 wv = *(const float4*)(wr[r] + k0);
                    acc[r] += wv.x*x0 + wv.y*x1 + wv.z*x2 + wv.w*x3;
                }
            }
        }
        // pass B: h-part
        for (int k0 = kbeg; k0 < kend; k0 += 4) {
            float x0 = cload(&hT[(k0+0)*B + bb]), x1 = cload(&hT[(k0+1)*B + bb]);
            float x2 = cload(&hT[(k0+2)*B + bb]), x3 = cload(&hT[(k0+3)*B + bb]);
            #pragma unroll
            for (int r = 0; r < 16; ++r) {
                float4 wv = *(const float4*)(hr[r] + k0);
                acc[r] += wv.x*x0 + wv.y*x1 + wv.z*x2 + wv.w*x3;
            }
        }

        #pragma unroll
        for (int r = 0; r < 16; ++r) gbuf[r][ks][lane] = acc[r];
        if (decrow) decbuf[ks][lane] = accd;
        __syncthreads();

        if (tid < 256) {
            int mi = tid >> 6, b = tid & 63;
            int bbo = (bh << 6) + b;
            int m = m0 + mi;
            float g[4];
            #pragma unroll
            for (int q = 0; q < 4; ++q) {
                int j = q*H + m;
                float s = biasPB ? biasPB[(size_t)j*B + bbo] : (bia[j] + bib[j]);
                #pragma unroll
                for (int k2 = 0; k2 < 8; ++k2) s += gbuf[q*4+mi][k2][b];
                g[q] = s;
            }
            float ig = 1.f/(1.f+expf(-g[0]));
            float fg = 1.f/(1.f+expf(-g[1]));
            float gv = tanhf(g[2]);
            float og = 1.f/(1.f+expf(-g[3]));
            int idx = m*B + bbo;
            float cn = fg*cc[idx] + ig*gv;      // c: WG-private, plain cached
            cc[idx] = cn;
            cstore(&hh[idx], og*tanhf(cn));     // h: cross-WG, coherent store
        }
        if (decrow && dout && tid < 64) {
            float s = decb;
            #pragma unroll
            for (int k2 = 0; k2 < 8; ++k2) s += decbuf[k2][tid];
            dout[(size_t)((bh<<6) + tid) * (T*O)] = s;
        }
    };

    for (int t = 0; t < T; ++t) {
        // L0: x = h2(t-1) via folded W0eff; logits(t-1) piggyback
        phase(h2p, h0p, p.W0eff, p.w_hh0,
              (t == 0) ? p.biasA : p.biasB, nullptr, nullptr,
              c0, h0c,
              (t > 0) ? decrow_w : nullptr,
              (t > 0 && isdec) ? (p.out + (size_t)(t-1)*O + rg) : nullptr);
        gbar();
        // L1
        phase(h0c, h1p, p.w_ihr, p.w_hhr, nullptr, p.b_ihr, p.b_hhr,
              c1, h1c, nullptr, nullptr);
        gbar();
        // L2
        phase(h1c, h2p, p.w_ihr + (size_t)G*H, p.w_hhr + (size_t)G*H, nullptr,
              p.b_ihr + G, p.b_hhr + G, c2, h2c, nullptr, nullptr);
        gbar();

        float* tp;
        tp = h0p; h0p = h0c; h0c = tp;
        tp = h1p; h1p = h1c; h1c = tp;
        tp = h2p; h2p = h2c; h2c = tp;
    }

    // final logits: out[:, 63, :] = dec(h2(63)) ; h2p == h2(63) after swap
    if (isdec) {
        float accd = 0.f;
        for (int k0 = ks*64; k0 < ks*64 + 64; k0 += 4) {
            float x0 = cload(&h2p[(k0+0)*B + bb]), x1 = cload(&h2p[(k0+1)*B + bb]);
            float x2 = cload(&h2p[(k0+2)*B + bb]), x3 = cload(&h2p[(k0+3)*B + bb]);
            float4 dv = *(const float4*)(decrow_w + k0);
            accd += dv.x*x0 + dv.y*x1 + dv.z*x2 + dv.w*x3;
        }
        decbuf[ks][lane] = accd;
        __syncthreads();
        if (tid < 64) {
            float s = decb;
            #pragma unroll
            for (int k2 = 0; k2 < 8; ++k2) s += decbuf[k2][tid];
            p.out[((size_t)((bh<<6) + tid) * T + 63) * O + rg] = s;
        }
    }
}

// ===========================================================================
// LEGACY FALLBACK (round-0, proven correct) — used only if ws_size too small
// ===========================================================================

__global__ __launch_bounds__(256) void init_kernel(
    const float* __restrict__ enc_w, const float* __restrict__ enc_b,
    float* __restrict__ nxtT, float* __restrict__ hbufs, float* __restrict__ cbufs)
{
    int idx = blockIdx.x * 256 + threadIdx.x;
    #pragma unroll
    for (int i = 0; i < 6; ++i) hbufs[i * HB + idx] = 0.f;
    #pragma unroll
    for (int i = 0; i < 3; ++i) cbufs[i * HB + idx] = 0.f;
    int h = idx >> 7;
    nxtT[idx] = enc_w[h * O + 1] + enc_b[h];
}

__global__ __launch_bounds__(256) void transpose_kernel(
    const float* __restrict__ dec_w, const float* __restrict__ enc_w,
    float* __restrict__ dec_wT, float* __restrict__ enc_wT)
{
    int idx = blockIdx.x * 256 + threadIdx.x;
    if (idx < O * H) {
        int o = idx / H, k = idx - o * H;
        dec_wT[k * O + o] = dec_w[o * H + k];
        enc_wT[o * H + k] = enc_w[k * O + o];
    }
}

__global__ __launch_bounds__(512) void gates_kernel(
    const float* __restrict__ xT, const float* __restrict__ hT,
    const float* __restrict__ w_ih, int ldih,
    const float* __restrict__ w_hh,
    const float* __restrict__ b_ih, const float* __restrict__ b_hh,
    const float* __restrict__ props,
    float* __restrict__ c, float* __restrict__ hout)
{
    const int wg = blockIdx.x;
    const int bg = wg >> 7, jg = wg & 127;
    const int m0 = jg * 4;
    const int lane_b = threadIdx.x & 63, ks = threadIdx.x >> 6;
    const int bb = (bg << 6) + lane_b;
    float acc[16];
    #pragma unroll
    for (int r = 0; r < 16; ++r) acc[r] = 0.f;
    const float* wih_rows[16]; const float* whh_rows[16];
    #pragma unroll
    for (int q = 0; q < 4; ++q)
        #pragma unroll
        for (int mi = 0; mi < 4; ++mi) {
            int r = q * 4 + mi, j = q * H + m0 + mi;
            wih_rows[r] = w_ih + (size_t)j * ldih;
            whh_rows[r] = w_hh + (size_t)j * H;
        }
    const int kbeg = ks * 64, kend = ks * 64 + 64;
    for (int k0 = kbeg; k0 < kend; k0 += 4) {
        float x0 = xT[(k0+0)*B+bb], x1 = xT[(k0+1)*B+bb];
        float x2 = xT[(k0+2)*B+bb], x3 = xT[(k0+3)*B+bb];
        #pragma unroll
        for (int r = 0; r < 16; ++r) {
            float4 wv = *(const float4*)(wih_rows[r] + k0);
            acc[r] += wv.x*x0 + wv.y*x1 + wv.z*x2 + wv.w*x3;
        }
    }
    for (int k0 = kbeg; k0 < kend; k0 += 4) {
        float x0 = hT[(k0+0)*B+bb], x1 = hT[(k0+1)*B+bb];
        float x2 = hT[(k0+2)*B+bb], x3 = hT[(k0+3)*B+bb];
        #pragma unroll
        for (int r = 0; r < 16; ++r) {
            float4 wv = *(const float4*)(whh_rows[r] + k0);
            acc[r] += wv.x*x0 + wv.y*x1 + wv.z*x2 + wv.w*x3;
        }
    }
    __shared__ float gbuf[16][8][64];
    #pragma unroll
    for (int r = 0; r < 16; ++r) gbuf[r][ks][lane_b] = acc[r];
    __syncthreads();
    if (threadIdx.x < 256) {
        int mi = threadIdx.x >> 6, b = threadIdx.x & 63;
        int bbo = (bg << 6) + b, m = m0 + mi;
        float g[4];
        #pragma unroll
        for (int q = 0; q < 4; ++q) {
            int j = q * H + m;
            float s = b_ih[j] + b_hh[j];
            #pragma unroll
            for (int k2 = 0; k2 < 8; ++k2) s += gbuf[q*4+mi][k2][b];
            if (props) {
                const float* wp = w_ih + (size_t)j * ldih + H;
                const float* pp = props + bbo * PP;
                s += wp[0]*pp[0] + wp[1]*pp[1] + wp[2]*pp[2] + wp[3]*pp[3];
            }
            g[q] = s;
        }
        float ig = 1.f/(1.f+expf(-g[0]));
        float fg = 1.f/(1.f+expf(-g[1]));
        float gv = tanhf(g[2]);
        float og = 1.f/(1.f+expf(-g[3]));
        int idx = m * B + bbo;
        float cn = fg * c[idx] + ig * gv;
        c[idx] = cn;
        hout[idx] = og * tanhf(cn);
    }
}

__global__ __launch_bounds__(256) void decenc_kernel(
    const float* __restrict__ h2T, const float* __restrict__ dec_wT,
    const float* __restrict__ dec_b, const float* __restrict__ enc_wT,
    const float* __restrict__ enc_b, float* __restrict__ nxtT,
    float* __restrict__ out, int t)
{
    const int b = blockIdx.x;
    const int w = threadIdx.x >> 6, o = threadIdx.x & 63;
    __shared__ float red[4][64];
    __shared__ float lg[64];
    float p = 0.f;
    if (o < O)
        for (int k = w * 128; k < w * 128 + 128; ++k)
            p += h2T[k * B + b] * dec_wT[k * O + o];
    red[w][o] = p;
    __syncthreads();
    if (threadIdx.x < 64) {
        int oo = threadIdx.x;
        float s = 0.f;
        if (oo < O) {
            s = dec_b[oo] + red[0][oo] + red[1][oo] + red[2][oo] + red[3][oo];
            out[((size_t)b * T + t) * O + oo] = s;
        }
        lg[oo] = s;
    }
    __syncthreads();
    for (int h = threadIdx.x; h < H; h += 256) {
        float s = enc_b[h];
        #pragma unroll 1
        for (int oo = 0; oo < O; ++oo) s += lg[oo] * enc_wT[oo * H + h];
        nxtT[h * B + b] = s;
    }
}

// ===========================================================================
extern "C" void kernel_launch(void* const* d_in, const int* in_sizes, int n_in,
                              void* d_out, int out_size, void* d_ws, size_t ws_size,
                              hipStream_t stream) {
    const float* props = (const float*)d_in[1];
    const float* enc_w = (const float*)d_in[2];
    const float* enc_b = (const float*)d_in[3];
    const float* dec_w = (const float*)d_in[4];
    const float* dec_b = (const float*)d_in[5];
    const float* w_ih0 = (const float*)d_in[6];
    const float* w_hh0 = (const float*)d_in[7];
    const float* b_ih0 = (const float*)d_in[8];
    const float* b_hh0 = (const float*)d_in[9];
    const float* w_ihr = (const float*)d_in[10];
    const float* w_hhr = (const float*)d_in[11];
    const float* b_ihr = (const float*)d_in[12];
    const float* b_hhr = (const float*)d_in[13];

    float* ws = (float*)d_ws;

    // persistent-path workspace layout (floats)
    //  [0,6HB)      h ping-pong          [6HB,9HB)   c
    //  [9HB,13HB)   M (512x512)          [13HB,29HB) W0eff (2048x512)
    //  [29HB,33HB)  biasA                [33HB,37HB) biasB
    //  [37HB, +5120) d, nxt0, x0c, cd   [+5120, +5152) barrier counter
    const size_t NEED = ((size_t)37 * HB + 5120 + 32) * sizeof(float);

    if (ws_size >= NEED) {
        float* hbuf  = ws;
        float* cbuf  = ws + 6*HB;
        float* M     = ws + 9*HB;
        float* W0eff = ws + 13*HB;
        float* biasA = ws + 29*HB;
        float* biasB = ws + 33*HB;
        float* dvec  = ws + 37*HB;
        float* nxt0  = dvec + 512;
        float* x0c   = nxt0 + 512;
        float* cd    = x0c + 2048;
        unsigned int* barcnt = (unsigned int*)(cd + 2048);

        k_init<<<256, 256, 0, stream>>>(enc_w, enc_b, dec_b, hbuf, cbuf, dvec, nxt0, barcnt);
        k_M<<<1024, 256, 0, stream>>>(enc_w, dec_w, M);
        k_cd<<<8, 256, 0, stream>>>(w_ih0, nxt0, dvec, x0c, cd);
        k_W0eff<<<128, 256, 0, stream>>>(w_ih0, M, W0eff);
        k_bias<<<1024, 256, 0, stream>>>(w_ih0, props, b_ih0, b_hh0, x0c, cd, biasA, biasB);

        RnnParams prm;
        prm.w_hh0 = w_hh0; prm.w_ihr = w_ihr; prm.w_hhr = w_hhr;
        prm.b_ihr = b_ihr; prm.b_hhr = b_hhr;
        prm.dec_w = dec_w; prm.dec_b = dec_b;
        prm.W0eff = W0eff; prm.biasA = biasA; prm.biasB = biasB;
        prm.h = hbuf; prm.c = cbuf; prm.out = (float*)d_out;
        prm.barcnt = barcnt;

        void* args[] = { &prm };
        hipLaunchCooperativeKernel((const void*)rnn_persistent,
                                   dim3(256), dim3(512), args, 0, stream);
        return;
    }

    // ---- legacy multi-launch fallback ----
    float* nxtT   = ws;
    float* hb     = ws + HB;
    float* cb     = ws + 7*HB;
    float* dec_wT = ws + 10*HB;
    float* enc_wT = dec_wT + H*O;

    init_kernel<<<256, 256, 0, stream>>>(enc_w, enc_b, nxtT, hb, cb);
    transpose_kernel<<<(O*H + 255)/256, 256, 0, stream>>>(dec_w, enc_w, dec_wT, enc_wT);

    float* hprev[3]; float* hcur[3];
    for (int l = 0; l < 3; ++l) { hprev[l] = hb + (2*l)*HB; hcur[l] = hb + (2*l+1)*HB; }

    for (int t = 0; t < T; ++t) {
        gates_kernel<<<256, 512, 0, stream>>>(nxtT, hprev[0], w_ih0, H+PP, w_hh0,
                                              b_ih0, b_hh0, props, cb, hcur[0]);
        gates_kernel<<<256, 512, 0, stream>>>(hcur[0], hprev[1], w_ihr, H, w_hhr,
                                              b_ihr, b_hhr, nullptr, cb + HB, hcur[1]);
        gates_kernel<<<256, 512, 0, stream>>>(hcur[1], hprev[2], w_ihr + (size_t)G*H, H,
                                              w_hhr + (size_t)G*H, b_ihr + G, b_hhr + G,
                                              nullptr, cb + 2*HB, hcur[2]);
        decenc_kernel<<<B, 256, 0, stream>>>(hcur[2], dec_wT, dec_b, enc_wT, enc_b,
                                             nxtT, (float*)d_out, t);
        for (int l = 0; l < 3; ++l) { float* tp = hprev[l]; hprev[l] = hcur[l]; hcur[l] = tp; }
    }
}

// Round 5
// 5093.520 us; speedup vs baseline: 5.1695x; 2.0765x over previous
//
#include <hip/hip_runtime.h>
#include <hip/hip_bf16.h>
#include <math.h>

// Problem dims (fixed by reference)
#define B 128
#define T 64
#define H 512
#define O 47
#define PP 4
#define G 2048         // 4*H
#define GH (G*H)
#define HB (H*B)       // 65536

// ===========================================================================
// PERSISTENT PATH, round 5: all weights LDS-resident.
// ---------------------------------------------------------------------------
// Round-4 counters: FETCH_SIZE 1.13 GB == 192 phases x 5.9 MB — weights miss
// L2 every phase (structural thrash: ~3.8 MB/XCD rotating set + pow2 set
// aliasing), pacing the kernel at 55us/phase. Fix: each WG owns 8 gate rows
// (2 hidden units) x ALL 128 batches; its weights for ALL 3 phases = 96 KB
// live in LDS, loaded once. Weights never touch L2 again.
//  - 256 WGs x 512 thr, 1 WG/CU (142 KB dynamic LDS).
//  - thread (b2=tid&63 -> batches 2b2,2b2+1 via 8B coherent loads;
//    ks=tid>>6 -> 64-wide k slice per GEMM part).
//  - weights read as ds_read_b128 wave-broadcast (conflict-free).
//  - state h: cload/cstore relaxed agent atomics (round-4, proven correct);
//    c: WG-private plain cached.
//  - custom no-fence grid barrier (round-4, proven correct).
// Folding (round 1, verified): nxt = enc(dec(h2)) folded into W0eff + bias
// planes; logits ride phase L0; 3 phases/step, 192 barriers total.
// ===========================================================================

__device__ __forceinline__ float2 cload2(const float* p) {
    unsigned long long v = __hip_atomic_load((const unsigned long long*)p,
                                             __ATOMIC_RELAXED, __HIP_MEMORY_SCOPE_AGENT);
    union { unsigned long long u; float2 f; } c; c.u = v; return c.f;
}
__device__ __forceinline__ void cstore(float* p, float v) {
    __hip_atomic_store(p, v, __ATOMIC_RELAXED, __HIP_MEMORY_SCOPE_AGENT);
}

// LDS layout (floats)
#define SM_W      0            // [6][8][512]  (phase*2+part, row, k) = 24576
#define SM_BIAS   24576        // [2][8][128]  biasA/biasB planes     = 2048
#define SM_DEC    26624        // [512] dec row
#define SM_BL     27136        // [2][8] L1/L2 scalar biases (pad to 27152)
#define SM_GBUF   27152        // float2[8][8][64] = 8192 floats
#define SM_DECB   35344        // float2[8][64]    = 1024 floats
#define SM_TOTAL  36368        // floats -> 145472 bytes

struct RnnParams {
  const float* w_hh0;   // [G][H]
  const float* w_ihr;   // [2][G][H]
  const float* w_hhr;   // [2][G][H]
  const float* b_ihr;   // [2][G]
  const float* b_hhr;   // [2][G]
  const float* dec_w;   // [O][H]
  const float* dec_b;   // [O]
  const float* W0eff;   // [G][H]
  const float* biasA;   // [G][B]
  const float* biasB;   // [G][B]
  float* h;             // 6*HB
  float* c;             // 3*HB
  float* out;           // [B][T][O]
  unsigned int* barcnt;
};

// ---- precompute kernels (round 1, verified) --------------------------------

__global__ __launch_bounds__(256) void k_init(
    const float* __restrict__ enc_w, const float* __restrict__ enc_b,
    const float* __restrict__ dec_b,
    float* __restrict__ h, float* __restrict__ c,
    float* __restrict__ d, float* __restrict__ nxt0,
    unsigned int* __restrict__ barcnt)
{
    int idx = blockIdx.x * 256 + threadIdx.x;
    if (idx == 0) *barcnt = 0u;
    #pragma unroll
    for (int i = 0; i < 6; ++i) h[i*HB + idx] = 0.f;
    #pragma unroll
    for (int i = 0; i < 3; ++i) c[i*HB + idx] = 0.f;
    if (idx < H) {
        float s = 0.f;
        for (int o = 0; o < O; ++o) s += enc_w[idx*O + o] * dec_b[o];
        d[idx] = enc_b[idx] + s;
        nxt0[idx] = enc_w[idx*O + 1] + enc_b[idx];
    }
}

__global__ __launch_bounds__(256) void k_M(
    const float* __restrict__ enc_w, const float* __restrict__ dec_w,
    float* __restrict__ M)
{
    int idx = blockIdx.x * 256 + threadIdx.x;
    int hh = idx >> 9, k = idx & 511;
    float s = 0.f;
    for (int o = 0; o < O; ++o) s += enc_w[hh*O + o] * dec_w[o*H + k];
    M[hh*H + k] = s;
}

__global__ __launch_bounds__(256) void k_cd(
    const float* __restrict__ w_ih0,
    const float* __restrict__ nxt0, const float* __restrict__ d,
    float* __restrict__ x0c, float* __restrict__ cd)
{
    int j = blockIdx.x * 256 + threadIdx.x;
    const float* row = w_ih0 + (size_t)j * (H + PP);
    float sA = 0.f, sB = 0.f;
    for (int k = 0; k < H; ++k) { float w = row[k]; sA += w * nxt0[k]; sB += w * d[k]; }
    x0c[j] = sA; cd[j] = sB;
}

__global__ __launch_bounds__(256) void k_W0eff(
    const float* __restrict__ w_ih0, const float* __restrict__ M,
    float* __restrict__ W0eff)
{
    int k0 = (threadIdx.x & 127) * 4;
    int jsub = threadIdx.x >> 7;
    int j0 = blockIdx.x * 16 + jsub * 8;
    float4 a[8];
    #pragma unroll
    for (int i = 0; i < 8; ++i) a[i] = make_float4(0.f, 0.f, 0.f, 0.f);
    for (int hh = 0; hh < H; ++hh) {
        float4 mv = *(const float4*)(M + (size_t)hh * H + k0);
        #pragma unroll
        for (int i = 0; i < 8; ++i) {
            float w = w_ih0[(size_t)(j0 + i) * (H + PP) + hh];
            a[i].x += w * mv.x; a[i].y += w * mv.y;
            a[i].z += w * mv.z; a[i].w += w * mv.w;
        }
    }
    #pragma unroll
    for (int i = 0; i < 8; ++i)
        *(float4*)(W0eff + (size_t)(j0 + i) * H + k0) = a[i];
}

__global__ __launch_bounds__(256) void k_bias(
    const float* __restrict__ w_ih0, const float* __restrict__ props,
    const float* __restrict__ b_ih0, const float* __restrict__ b_hh0,
    const float* __restrict__ x0c, const float* __restrict__ cd,
    float* __restrict__ biasA, float* __restrict__ biasB)
{
    int idx = blockIdx.x * 256 + threadIdx.x;
    int j = idx >> 7, b = idx & 127;
    const float* wp = w_ih0 + (size_t)j * (H + PP) + H;
    const float* pr = props + b * PP;
    float pc = wp[0]*pr[0] + wp[1]*pr[1] + wp[2]*pr[2] + wp[3]*pr[3];
    float base = b_ih0[j] + b_hh0[j] + pc;
    biasA[idx] = base + x0c[j];
    biasB[idx] = base + cd[j];
}

// ---- the persistent kernel -------------------------------------------------

__global__ __launch_bounds__(512) void rnn_persistent(RnnParams p)
{
    extern __shared__ float sm[];
    const int tid = threadIdx.x;
    const int rg  = blockIdx.x;        // [0,256): owns units 2rg, 2rg+1
    const int u0  = rg * 2;
    const int b2  = tid & 63;          // lane -> batches 2b2, 2b2+1
    const int ks  = tid >> 6;          // wave index == k-slice [0,8)

    float* sW    = sm + SM_W;          // [s][r][k], s = phase*2+part
    float* sBias = sm + SM_BIAS;       // [pl][r][b]
    float* sDec  = sm + SM_DEC;
    float* sBL   = sm + SM_BL;
    float2* sGbuf = (float2*)(sm + SM_GBUF);   // [r][ks][b2]
    float2* sDecb = (float2*)(sm + SM_DECB);   // [ks][b2]

    float* h0p = p.h + 0*HB; float* h0c = p.h + 1*HB;
    float* h1p = p.h + 2*HB; float* h1c = p.h + 3*HB;
    float* h2p = p.h + 4*HB; float* h2c = p.h + 5*HB;
    float* c0 = p.c; float* c1 = p.c + HB; float* c2 = p.c + 2*HB;

    const bool  isdec = (rg < O);
    const float decb  = isdec ? p.dec_b[rg] : 0.f;

    // ---- one-time weight preload into LDS (own rows only; no grid dep) ----
    #pragma unroll
    for (int r = 0; r < 8; ++r) {
        int j = (r >> 1) * H + u0 + (r & 1);
        const float* s0 = p.W0eff + (size_t)j * H;
        const float* s1 = p.w_hh0 + (size_t)j * H;
        const float* s2 = p.w_ihr + (size_t)j * H;
        const float* s3 = p.w_hhr + (size_t)j * H;
        const float* s4 = p.w_ihr + (size_t)GH + (size_t)j * H;
        const float* s5 = p.w_hhr + (size_t)GH + (size_t)j * H;
        sW[(0*8 + r)*512 + tid] = s0[tid];
        sW[(1*8 + r)*512 + tid] = s1[tid];
        sW[(2*8 + r)*512 + tid] = s2[tid];
        sW[(3*8 + r)*512 + tid] = s3[tid];
        sW[(4*8 + r)*512 + tid] = s4[tid];
        sW[(5*8 + r)*512 + tid] = s5[tid];
    }
    for (int idx = tid; idx < 2048; idx += 512) {
        int pl = idx >> 10, r = (idx >> 7) & 7, b = idx & 127;
        int j = (r >> 1) * H + u0 + (r & 1);
        sBias[idx] = (pl ? p.biasB : p.biasA)[(size_t)j * B + b];
    }
    if (tid < 16) {
        int l = tid >> 3, r = tid & 7;
        int j = (r >> 1) * H + u0 + (r & 1);
        sBL[tid] = p.b_ihr[l*G + j] + p.b_hhr[l*G + j];
    }
    if (isdec) sDec[tid] = p.dec_w[(size_t)rg * H + tid];
    __syncthreads();

    unsigned int bartgt = 0;
    unsigned int* cnt = p.barcnt;
    auto gbar = [&]() {
        bartgt += 256;
        __syncthreads();   // compiler drains vmcnt here -> cstores complete
        if (tid == 0) {
            __hip_atomic_fetch_add(cnt, 1u, __ATOMIC_RELEASE, __HIP_MEMORY_SCOPE_AGENT);
            while (__hip_atomic_load(cnt, __ATOMIC_RELAXED, __HIP_MEMORY_SCOPE_AGENT) < bartgt)
                __builtin_amdgcn_s_sleep(1);
        }
        __syncthreads();
    };

    auto phase = [&](const float* __restrict__ xT, const float* __restrict__ hT,
                     int ph, const float* biasPlane, const float* biasScal,
                     float* cc, float* hh, bool dopig, float* dout) {
        float2 acc[8];
        #pragma unroll
        for (int r = 0; r < 8; ++r) { acc[r].x = 0.f; acc[r].y = 0.f; }
        float2 accd; accd.x = 0.f; accd.y = 0.f;

        const float* wx = sW + (ph*2 + 0) * 8 * 512;
        const float* wh = sW + (ph*2 + 1) * 8 * 512;
        const int kb = ks * 64;
        const int xoff = 2 * b2;

        // x-part (+ dec piggyback on the same x loads)
        for (int k0 = kb; k0 < kb + 64; k0 += 4) {
            float2 x0 = cload2(xT + (k0+0)*B + xoff);
            float2 x1 = cload2(xT + (k0+1)*B + xoff);
            float2 x2 = cload2(xT + (k0+2)*B + xoff);
            float2 x3 = cload2(xT + (k0+3)*B + xoff);
            #pragma unroll
            for (int r = 0; r < 8; ++r) {
                float4 w = *(const float4*)(wx + r*512 + k0);   // broadcast
                acc[r].x += w.x*x0.x + w.y*x1.x + w.z*x2.x + w.w*x3.x;
                acc[r].y += w.x*x0.y + w.y*x1.y + w.z*x2.y + w.w*x3.y;
            }
            if (dopig) {
                float4 w = *(const float4*)(sDec + k0);
                accd.x += w.x*x0.x + w.y*x1.x + w.z*x2.x + w.w*x3.x;
                accd.y += w.x*x0.y + w.y*x1.y + w.z*x2.y + w.w*x3.y;
            }
        }
        // h-part
        for (int k0 = kb; k0 < kb + 64; k0 += 4) {
            float2 x0 = cload2(hT + (k0+0)*B + xoff);
            float2 x1 = cload2(hT + (k0+1)*B + xoff);
            float2 x2 = cload2(hT + (k0+2)*B + xoff);
            float2 x3 = cload2(hT + (k0+3)*B + xoff);
            #pragma unroll
            for (int r = 0; r < 8; ++r) {
                float4 w = *(const float4*)(wh + r*512 + k0);
                acc[r].x += w.x*x0.x + w.y*x1.x + w.z*x2.x + w.w*x3.x;
                acc[r].y += w.x*x0.y + w.y*x1.y + w.z*x2.y + w.w*x3.y;
            }
        }

        #pragma unroll
        for (int r = 0; r < 8; ++r) sGbuf[(r*8 + ks)*64 + b2] = acc[r];
        if (dopig) sDecb[ks*64 + b2] = accd;
        __syncthreads();

        if (tid < 256) {
            int mi = tid >> 7, b = tid & 127;
            int u = u0 + mi;
            float g[4];
            #pragma unroll
            for (int q = 0; q < 4; ++q) {
                int r = q*2 + mi;
                float s = biasPlane ? biasPlane[r*128 + b] : biasScal[r];
                #pragma unroll
                for (int k2 = 0; k2 < 8; ++k2) {
                    float2 v = sGbuf[(r*8 + k2)*64 + (b >> 1)];
                    s += (b & 1) ? v.y : v.x;
                }
                g[q] = s;
            }
            float ig = 1.f/(1.f+expf(-g[0]));
            float fg = 1.f/(1.f+expf(-g[1]));
            float gv = tanhf(g[2]);
            float og = 1.f/(1.f+expf(-g[3]));
            int idx = u*B + b;
            float cn = fg*cc[idx] + ig*gv;
            cc[idx] = cn;
            cstore(&hh[idx], og*tanhf(cn));
        } else if (dopig && tid < 384) {
            int b = tid - 256;
            float s = decb;
            #pragma unroll
            for (int k2 = 0; k2 < 8; ++k2) {
                float2 v = sDecb[k2*64 + (b >> 1)];
                s += (b & 1) ? v.y : v.x;
            }
            dout[(size_t)b * (T*O)] = s;
        }
        // no trailing sync needed: gbar() after each phase starts with one
    };

    for (int t = 0; t < T; ++t) {
        bool pig = (t > 0) && isdec;
        phase(h2p, h0p, 0, sBias + (t == 0 ? 0 : 1024), nullptr,
              c0, h0c, pig, pig ? (p.out + (size_t)(t-1)*O + rg) : nullptr);
        gbar();
        phase(h0c, h1p, 1, nullptr, sBL, c1, h1c, false, nullptr);
        gbar();
        phase(h1c, h2p, 2, nullptr, sBL + 8, c2, h2c, false, nullptr);
        gbar();
        float* tp;
        tp = h0p; h0p = h0c; h0c = tp;
        tp = h1p; h1p = h1c; h1c = tp;
        tp = h2p; h2p = h2c; h2c = tp;
    }

    // final logits: out[:,63,:] = dec(h2(63)); h2p == h2(63) after swap
    {
        float2 accd; accd.x = 0.f; accd.y = 0.f;
        if (isdec) {
            const int kb = ks * 64;
            const int xoff = 2 * b2;
            for (int k0 = kb; k0 < kb + 64; k0 += 4) {
                float2 x0 = cload2(h2p + (k0+0)*B + xoff);
                float2 x1 = cload2(h2p + (k0+1)*B + xoff);
                float2 x2 = cload2(h2p + (k0+2)*B + xoff);
                float2 x3 = cload2(h2p + (k0+3)*B + xoff);
                float4 w = *(const float4*)(sDec + k0);
                accd.x += w.x*x0.x + w.y*x1.x + w.z*x2.x + w.w*x3.x;
                accd.y += w.x*x0.y + w.y*x1.y + w.z*x2.y + w.w*x3.y;
            }
            sDecb[ks*64 + b2] = accd;
        }
        __syncthreads();
        if (isdec && tid < 128) {
            int b = tid;
            float s = decb;
            #pragma unroll
            for (int k2 = 0; k2 < 8; ++k2) {
                float2 v = sDecb[k2*64 + (b >> 1)];
                s += (b & 1) ? v.y : v.x;
            }
            p.out[((size_t)b * T + 63) * O + rg] = s;
        }
    }
}

// ===========================================================================
// LEGACY FALLBACK (round-0, proven correct) — used only if ws_size too small
// ===========================================================================

__global__ __launch_bounds__(256) void init_kernel(
    const float* __restrict__ enc_w, const float* __restrict__ enc_b,
    float* __restrict__ nxtT, float* __restrict__ hbufs, float* __restrict__ cbufs)
{
    int idx = blockIdx.x * 256 + threadIdx.x;
    #pragma unroll
    for (int i = 0; i < 6; ++i) hbufs[i * HB + idx] = 0.f;
    #pragma unroll
    for (int i = 0; i < 3; ++i) cbufs[i * HB + idx] = 0.f;
    int h = idx >> 7;
    nxtT[idx] = enc_w[h * O + 1] + enc_b[h];
}

__global__ __launch_bounds__(256) void transpose_kernel(
    const float* __restrict__ dec_w, const float* __restrict__ enc_w,
    float* __restrict__ dec_wT, float* __restrict__ enc_wT)
{
    int idx = blockIdx.x * 256 + threadIdx.x;
    if (idx < O * H) {
        int o = idx / H, k = idx - o * H;
        dec_wT[k * O + o] = dec_w[o * H + k];
        enc_wT[o * H + k] = enc_w[k * O + o];
    }
}

__global__ __launch_bounds__(512) void gates_kernel(
    const float* __restrict__ xT, const float* __restrict__ hT,
    const float* __restrict__ w_ih, int ldih,
    const float* __restrict__ w_hh,
    const float* __restrict__ b_ih, const float* __restrict__ b_hh,
    const float* __restrict__ props,
    float* __restrict__ c, float* __restrict__ hout)
{
    const int wg = blockIdx.x;
    const int bg = wg >> 7, jg = wg & 127;
    const int m0 = jg * 4;
    const int lane_b = threadIdx.x & 63, ks = threadIdx.x >> 6;
    const int bb = (bg << 6) + lane_b;
    float acc[16];
    #pragma unroll
    for (int r = 0; r < 16; ++r) acc[r] = 0.f;
    const float* wih_rows[16]; const float* whh_rows[16];
    #pragma unroll
    for (int q = 0; q < 4; ++q)
        #pragma unroll
        for (int mi = 0; mi < 4; ++mi) {
            int r = q * 4 + mi, j = q * H + m0 + mi;
            wih_rows[r] = w_ih + (size_t)j * ldih;
            whh_rows[r] = w_hh + (size_t)j * H;
        }
    const int kbeg = ks * 64, kend = ks * 64 + 64;
    for (int k0 = kbeg; k0 < kend; k0 += 4) {
        float x0 = xT[(k0+0)*B+bb], x1 = xT[(k0+1)*B+bb];
        float x2 = xT[(k0+2)*B+bb], x3 = xT[(k0+3)*B+bb];
        #pragma unroll
        for (int r = 0; r < 16; ++r) {
            float4 wv = *(const float4*)(wih_rows[r] + k0);
            acc[r] += wv.x*x0 + wv.y*x1 + wv.z*x2 + wv.w*x3;
        }
    }
    for (int k0 = kbeg; k0 < kend; k0 += 4) {
        float x0 = hT[(k0+0)*B+bb], x1 = hT[(k0+1)*B+bb];
        float x2 = hT[(k0+2)*B+bb], x3 = hT[(k0+3)*B+bb];
        #pragma unroll
        for (int r = 0; r < 16; ++r) {
            float4 wv = *(const float4*)(whh_rows[r] + k0);
            acc[r] += wv.x*x0 + wv.y*x1 + wv.z*x2 + wv.w*x3;
        }
    }
    __shared__ float gbuf[16][8][64];
    #pragma unroll
    for (int r = 0; r < 16; ++r) gbuf[r][ks][lane_b] = acc[r];
    __syncthreads();
    if (threadIdx.x < 256) {
        int mi = threadIdx.x >> 6, b = threadIdx.x & 63;
        int bbo = (bg << 6) + b, m = m0 + mi;
        float g[4];
        #pragma unroll
        for (int q = 0; q < 4; ++q) {
            int j = q * H + m;
            float s = b_ih[j] + b_hh[j];
            #pragma unroll
            for (int k2 = 0; k2 < 8; ++k2) s += gbuf[q*4+mi][k2][b];
            if (props) {
                const float* wp = w_ih + (size_t)j * ldih + H;
                const float* pp = props + bbo * PP;
                s += wp[0]*pp[0] + wp[1]*pp[1] + wp[2]*pp[2] + wp[3]*pp[3];
            }
            g[q] = s;
        }
        float ig = 1.f/(1.f+expf(-g[0]));
        float fg = 1.f/(1.f+expf(-g[1]));
        float gv = tanhf(g[2]);
        float og = 1.f/(1.f+expf(-g[3]));
        int idx = m * B + bbo;
        float cn = fg * c[idx] + ig * gv;
        c[idx] = cn;
        hout[idx] = og * tanhf(cn);
    }
}

__global__ __launch_bounds__(256) void decenc_kernel(
    const float* __restrict__ h2T, const float* __restrict__ dec_wT,
    const float* __restrict__ dec_b, const float* __restrict__ enc_wT,
    const float* __restrict__ enc_b, float* __restrict__ nxtT,
    float* __restrict__ out, int t)
{
    const int b = blockIdx.x;
    const int w = threadIdx.x >> 6, o = threadIdx.x & 63;
    __shared__ float red[4][64];
    __shared__ float lg[64];
    float p = 0.f;
    if (o < O)
        for (int k = w * 128; k < w * 128 + 128; ++k)
            p += h2T[k * B + b] * dec_wT[k * O + o];
    red[w][o] = p;
    __syncthreads();
    if (threadIdx.x < 64) {
        int oo = threadIdx.x;
        float s = 0.f;
        if (oo < O) {
            s = dec_b[oo] + red[0][oo] + red[1][oo] + red[2][oo] + red[3][oo];
            out[((size_t)b * T + t) * O + oo] = s;
        }
        lg[oo] = s;
    }
    __syncthreads();
    for (int h = threadIdx.x; h < H; h += 256) {
        float s = enc_b[h];
        #pragma unroll 1
        for (int oo = 0; oo < O; ++oo) s += lg[oo] * enc_wT[oo * H + h];
        nxtT[h * B + b] = s;
    }
}

// ===========================================================================
extern "C" void kernel_launch(void* const* d_in, const int* in_sizes, int n_in,
                              void* d_out, int out_size, void* d_ws, size_t ws_size,
                              hipStream_t stream) {
    const float* props = (const float*)d_in[1];
    const float* enc_w = (const float*)d_in[2];
    const float* enc_b = (const float*)d_in[3];
    const float* dec_w = (const float*)d_in[4];
    const float* dec_b = (const float*)d_in[5];
    const float* w_ih0 = (const float*)d_in[6];
    const float* w_hh0 = (const float*)d_in[7];
    const float* b_ih0 = (const float*)d_in[8];
    const float* b_hh0 = (const float*)d_in[9];
    const float* w_ihr = (const float*)d_in[10];
    const float* w_hhr = (const float*)d_in[11];
    const float* b_ihr = (const float*)d_in[12];
    const float* b_hhr = (const float*)d_in[13];

    float* ws = (float*)d_ws;
    const size_t NEED = ((size_t)37 * HB + 5120 + 32) * sizeof(float);
    const size_t LDS_BYTES = (size_t)SM_TOTAL * sizeof(float);

    static int lds_attr_set = -1;
    if (lds_attr_set < 0) {
        lds_attr_set = (hipFuncSetAttribute((const void*)rnn_persistent,
                         hipFuncAttributeMaxDynamicSharedMemorySize,
                         (int)LDS_BYTES) == hipSuccess) ? 1 : 0;
    }

    if (ws_size >= NEED && lds_attr_set == 1) {
        float* hbuf  = ws;
        float* cbuf  = ws + 6*HB;
        float* M     = ws + 9*HB;
        float* W0eff = ws + 13*HB;
        float* biasA = ws + 29*HB;
        float* biasB = ws + 33*HB;
        float* dvec  = ws + 37*HB;
        float* nxt0  = dvec + 512;
        float* x0c   = nxt0 + 512;
        float* cd    = x0c + 2048;
        unsigned int* barcnt = (unsigned int*)(cd + 2048);

        k_init<<<256, 256, 0, stream>>>(enc_w, enc_b, dec_b, hbuf, cbuf, dvec, nxt0, barcnt);
        k_M<<<1024, 256, 0, stream>>>(enc_w, dec_w, M);
        k_cd<<<8, 256, 0, stream>>>(w_ih0, nxt0, dvec, x0c, cd);
        k_W0eff<<<128, 256, 0, stream>>>(w_ih0, M, W0eff);
        k_bias<<<1024, 256, 0, stream>>>(w_ih0, props, b_ih0, b_hh0, x0c, cd, biasA, biasB);

        RnnParams prm;
        prm.w_hh0 = w_hh0; prm.w_ihr = w_ihr; prm.w_hhr = w_hhr;
        prm.b_ihr = b_ihr; prm.b_hhr = b_hhr;
        prm.dec_w = dec_w; prm.dec_b = dec_b;
        prm.W0eff = W0eff; prm.biasA = biasA; prm.biasB = biasB;
        prm.h = hbuf; prm.c = cbuf; prm.out = (float*)d_out;
        prm.barcnt = barcnt;

        void* args[] = { &prm };
        hipLaunchCooperativeKernel((const void*)rnn_persistent,
                                   dim3(256), dim3(512), args,
                                   (unsigned int)LDS_BYTES, stream);
        return;
    }

    // ---- legacy multi-launch fallback ----
    float* nxtT   = ws;
    float* hb     = ws + HB;
    float* cb     = ws + 7*HB;
    float* dec_wT = ws + 10*HB;
    float* enc_wT = dec_wT + H*O;

    init_kernel<<<256, 256, 0, stream>>>(enc_w, enc_b, nxtT, hb, cb);
    transpose_kernel<<<(O*H + 255)/256, 256, 0, stream>>>(dec_w, enc_w, dec_wT, enc_wT);

    float* hprev[3]; float* hcur[3];
    for (int l = 0; l < 3; ++l) { hprev[l] = hb + (2*l)*HB; hcur[l] = hb + (2*l+1)*HB; }

    for (int t = 0; t < T; ++t) {
        gates_kernel<<<256, 512, 0, stream>>>(nxtT, hprev[0], w_ih0, H+PP, w_hh0,
                                              b_ih0, b_hh0, props, cb, hcur[0]);
        gates_kernel<<<256, 512, 0, stream>>>(hcur[0], hprev[1], w_ihr, H, w_hhr,
                                              b_ihr, b_hhr, nullptr, cb + HB, hcur[1]);
        gates_kernel<<<256, 512, 0, stream>>>(hcur[1], hprev[2], w_ihr + (size_t)G*H, H,
                                              w_hhr + (size_t)G*H, b_ihr + G, b_hhr + G,
                                              nullptr, cb + 2*HB, hcur[2]);
        decenc_kernel<<<B, 256, 0, stream>>>(hcur[2], dec_wT, dec_b, enc_wT, enc_b,
                                             nxtT, (float*)d_out, t);
        for (int l = 0; l < 3; ++l) { float* tp = hprev[l]; hprev[l] = hcur[l]; hcur[l] = tp; }
    }
}